// Round 5
// baseline (181.197 us; speedup 1.0000x reference)
//
#include <hip/hip_runtime.h>

namespace {

constexpr int T_LEN = 512;
constexpr int XS    = 516;   // padded floats per x-row in LDS

typedef _Float16 half4  __attribute__((ext_vector_type(4)));
typedef _Float16 half8  __attribute__((ext_vector_type(8)));
typedef float    f32x4v __attribute__((ext_vector_type(4)));
typedef unsigned uint2v __attribute__((ext_vector_type(2)));
typedef unsigned uint4v __attribute__((ext_vector_type(4)));

#define MFMA32(a, b, c) __builtin_amdgcn_mfma_f32_16x16x32_f16((a), (b), (c), 0, 0, 0)

// Load an fp16 A-fragment from a row-major 64x64 fp32 matrix, scaled.
// Lane holds A[row, k0 .. k0+7].
__device__ __forceinline__ half8 load_frag(const float* __restrict__ W,
                                           int row, int k0, float s) {
    const float* p = W + row * 64 + k0;
    f32x4v lo = *reinterpret_cast<const f32x4v*>(p);
    f32x4v hi = *reinterpret_cast<const f32x4v*>(p + 4);
    uint4v u;
    u.x = __builtin_bit_cast(unsigned, __builtin_amdgcn_cvt_pkrtz(lo.x * s, lo.y * s));
    u.y = __builtin_bit_cast(unsigned, __builtin_amdgcn_cvt_pkrtz(lo.z * s, lo.w * s));
    u.z = __builtin_bit_cast(unsigned, __builtin_amdgcn_cvt_pkrtz(hi.x * s, hi.y * s));
    u.w = __builtin_bit_cast(unsigned, __builtin_amdgcn_cvt_pkrtz(hi.z * s, hi.w * s));
    return __builtin_bit_cast(half8, u);
}

// a holds 2*preact; tanh(y) = 1 - 2/(exp(2y)+1), robust at +-inf.
__device__ __forceinline__ void tanh4(f32x4v &a) {
#pragma unroll
    for (int q = 0; q < 4; ++q) {
        float e = __expf(a[q]);
        a[q] = 1.0f - 2.0f * __builtin_amdgcn_rcpf(e + 1.0f);
    }
}

__global__ __launch_bounds__(512, 2)
void rnn_split_kernel(const float* __restrict__ x,
                      const float* __restrict__ Wih0,
                      const float* __restrict__ Whh0,
                      const float* __restrict__ bih0,
                      const float* __restrict__ bhh0,
                      const float* __restrict__ Wih1,
                      const float* __restrict__ Whh1,
                      const float* __restrict__ bih1,
                      const float* __restrict__ bhh1,
                      const float* __restrict__ fc1W,
                      const float* __restrict__ fc1b,
                      const float* __restrict__ fc2W,
                      const float* __restrict__ fc2b,
                      float* __restrict__ out)
{
    const int tid    = threadIdx.x;        // 512 threads = 8 waves
    const int wave   = tid >> 6;
    const int grp    = wave >> 2;          // 0: layer-0 waves, 1: layer-1 waves
    const int wv     = wave & 3;           // owns hidden rows 16wv..16wv+15
    const int lane   = tid & 63;
    const int g      = lane >> 4;
    const int b16    = lane & 15;          // batch within 16-batch tile
    const int batch0 = blockIdx.x * 16;

    __shared__ float    sx[16 * XS];       // whole x tile, staged once
    __shared__ _Float16 sh1[2][16 * 72];   // h1 exchange, ping-pong (stride 72)
    __shared__ _Float16 sh2[2][16 * 72];   // h2 exchange
    __shared__ float    pf[4][16];         // fc2 partials

    // ---- stage x[batch0..+15][0..511] into LDS (coalesced f32x4) ----
    {
        const float* gx = x + (size_t)batch0 * T_LEN;
#pragma unroll
        for (int c = 0; c < 4; ++c) {
            int idx = tid + c * 512;            // float4 index 0..2047
            int r = idx >> 7, c4 = idx & 127;   // 128 float4 per row
            f32x4v v = *reinterpret_cast<const f32x4v*>(gx + r * T_LEN + c4 * 4);
            *reinterpret_cast<f32x4v*>(&sx[r * XS + c4 * 4]) = v;
        }
    }

    // ---- per-group persistent weights (x2 scale folds tanh's 2y) ----
    const int row = 16 * wv + b16;
    const int ro  = 16 * wv + 4 * g;       // own publish row offset

    half8 WA0_0 = {}, WA0_1 = {};          // layer-0 waves
    half8 WI1_0 = {}, WI1_1 = {}, WH1_0 = {}, WH1_1 = {};  // layer-1 waves
    f32x4v bb0 = {}, wx2 = {}, bb1 = {};

    if (grp == 0) {
        WA0_0 = load_frag(Whh0, row,      8 * g, 2.0f);
        WA0_1 = load_frag(Whh0, row, 32 + 8 * g, 2.0f);
#pragma unroll
        for (int q = 0; q < 4; ++q) {
            const int o = 16 * wv + 4 * g + q;
            bb0[q] = 2.0f * (bih0[o] + bhh0[o]);
            wx2[q] = 2.0f * Wih0[o];
        }
    } else {
        WI1_0 = load_frag(Wih1, row,      8 * g, 2.0f);
        WI1_1 = load_frag(Wih1, row, 32 + 8 * g, 2.0f);
        WH1_0 = load_frag(Whh1, row,      8 * g, 2.0f);
        WH1_1 = load_frag(Whh1, row, 32 + 8 * g, 2.0f);
#pragma unroll
        for (int q = 0; q < 4; ++q) {
            const int o = 16 * wv + 4 * g + q;
            bb1[q] = 2.0f * (bih1[o] + bhh1[o]);
        }
    }

    auto publish = [&](_Float16* base, const f32x4v& a) {
        uint2v p;
        p.x = __builtin_bit_cast(unsigned, __builtin_amdgcn_cvt_pkrtz(a[0], a[1]));
        p.y = __builtin_bit_cast(unsigned, __builtin_amdgcn_cvt_pkrtz(a[2], a[3]));
        *reinterpret_cast<uint2v*>(base + b16 * 72 + ro) = p;
    };
    auto rdfrag = [&](const _Float16* base, int k0) -> half8 {
        return *reinterpret_cast<const half8*>(base + b16 * 72 + k0);
    };

    // ---- tick 0: A publishes h1(-1)=0 then computes h1(0); B publishes h2(-1)=0
    if (grp == 0) {
        *reinterpret_cast<uint2v*>(&sh1[1][0] + b16 * 72 + ro) = uint2v{0, 0};
        const float x0 = sx[b16 * XS + 0];
        f32x4v a0 = wx2 * x0 + bb0;
        tanh4(a0);
        publish(sh1[0], a0);
    } else {
        *reinterpret_cast<uint2v*>(&sh2[0][0] + b16 * 72 + ro) = uint2v{0, 0};
    }
    __syncthreads();

    // ---- main: tick t: A computes h1(t), B computes h2(t-1); 1 barrier/tick
#pragma unroll 2
    for (int t = 1; t <= T_LEN; ++t) {
        const int s = t & 1;
        const int r = s ^ 1;
        if (grp == 0) {
            if (t < T_LEN) {
                half8 B0 = rdfrag(sh1[r],      8 * g);   // h1(t-1)
                half8 B1 = rdfrag(sh1[r], 32 + 8 * g);
                const float xt = sx[b16 * XS + t];
                f32x4v a0 = wx2 * xt + bb0;
                a0 = MFMA32(WA0_0, B0, a0);
                a0 = MFMA32(WA0_1, B1, a0);
                tanh4(a0);
                publish(sh1[s], a0);                     // h1(t)
            }
        } else {
            half8 B10 = rdfrag(sh1[r],      8 * g);      // h1(t-1)
            half8 B11 = rdfrag(sh1[r], 32 + 8 * g);
            half8 B20 = rdfrag(sh2[r],      8 * g);      // h2(t-2)
            half8 B21 = rdfrag(sh2[r], 32 + 8 * g);
            f32x4v zz = {};
            f32x4v u = MFMA32(WI1_0, B10, bb1);          // two parallel 2-chains
            u = MFMA32(WI1_1, B11, u);
            f32x4v v = MFMA32(WH1_0, B20, zz);
            v = MFMA32(WH1_1, B21, v);
            f32x4v a1 = u + v;
            tanh4(a1);
            publish(sh2[s], a1);                         // h2(t-1)
        }
        __syncthreads();
    }

    // final h2(511) was published at t=512 into sh2[0]

    // ---- fc1 + relu + fc2 (layer-0 waves, now idle, do it) ----
    if (grp == 0) {
        const half8 F0 = load_frag(fc1W, row,      8 * g, 1.0f);
        const half8 F1 = load_frag(fc1W, row, 32 + 8 * g, 1.0f);
        half8 E0 = rdfrag(sh2[0],      8 * g);
        half8 E1 = rdfrag(sh2[0], 32 + 8 * g);
        f32x4v zf;
#pragma unroll
        for (int q = 0; q < 4; ++q) zf[q] = fc1b[16 * wv + 4 * g + q];
        zf = MFMA32(F0, E0, zf);
        zf = MFMA32(F1, E1, zf);

        float pacc = 0.0f;
#pragma unroll
        for (int q = 0; q < 4; ++q)
            pacc += fmaxf(zf[q], 0.0f) * fc2W[16 * wv + 4 * g + q];
        pacc += __shfl_xor(pacc, 16);
        pacc += __shfl_xor(pacc, 32);
        if (lane < 16) pf[wv][lane] = pacc;
    }
    __syncthreads();
    if (tid < 16)
        out[batch0 + tid] = pf[0][tid] + pf[1][tid] + pf[2][tid] + pf[3][tid]
                          + fc2b[0];
}

} // namespace

extern "C" void kernel_launch(void* const* d_in, const int* in_sizes, int n_in,
                              void* d_out, int out_size, void* d_ws, size_t ws_size,
                              hipStream_t stream) {
    (void)n_in; (void)out_size; (void)d_ws; (void)ws_size;
    const float* x    = (const float*)d_in[0];
    const float* Wih0 = (const float*)d_in[1];
    const float* Whh0 = (const float*)d_in[2];
    const float* bih0 = (const float*)d_in[3];
    const float* bhh0 = (const float*)d_in[4];
    const float* Wih1 = (const float*)d_in[5];
    const float* Whh1 = (const float*)d_in[6];
    const float* bih1 = (const float*)d_in[7];
    const float* bhh1 = (const float*)d_in[8];
    const float* fc1W = (const float*)d_in[9];
    const float* fc1b = (const float*)d_in[10];
    const float* fc2W = (const float*)d_in[11];
    const float* fc2b = (const float*)d_in[12];
    float* out = (float*)d_out;

    const int B = in_sizes[0] / T_LEN;      // 4096
    dim3 grid(B / 16), block(512);
    rnn_split_kernel<<<grid, block, 0, stream>>>(
        x, Wih0, Whh0, bih0, bhh0, Wih1, Whh1, bih1, bhh1,
        fc1W, fc1b, fc2W, fc2b, out);
}